// Round 2
// baseline (7359.228 us; speedup 1.0000x reference)
//
#include <hip/hip_runtime.h>
#include <hip/hip_bf16.h>
#include <math.h>

typedef __hip_bfloat16 bf16;

#define B_   2
#define S_   2048
#define D_   1024
#define H_   16
#define DH_  64
#define BS_  4096   // B_*S_
#define D3_  3072   // 3*D_
#define DF_  4096   // 4*D_

__device__ __forceinline__ float tof(float v) { return v; }
__device__ __forceinline__ float tof(bf16 v) { return __bfloat162float(v); }
__device__ __forceinline__ void stf(float* p, size_t i, float v) { p[i] = v; }
__device__ __forceinline__ void stf(bf16* p, size_t i, float v) { p[i] = __float2bfloat16(v); }

// ---------------------------------------------------------------------------
// LayerNorm (optionally fused with residual add): one block per row of D_=1024
//   FUSE=false: h = LN(a)
//   FUSE=true : x2 = st*a + s1t*skip ; h = LN(x2) ; x2 written out (bf16)
// ---------------------------------------------------------------------------
template <bool FUSE, typename TA, typename TS>
__global__ __launch_bounds__(256) void resid_ln_kernel(
    const TA* __restrict__ a, const TS* __restrict__ skip,
    const float* __restrict__ w, const float* __restrict__ bias,
    bf16* __restrict__ x2, bf16* __restrict__ hout, float st, float s1t) {
  const int row = blockIdx.x;
  const int tid = threadIdx.x;
  const int base = tid * 4;
  const size_t roff = (size_t)row * D_;

  float xv[4];
#pragma unroll
  for (int i = 0; i < 4; i++) {
    float v = tof(a[roff + base + i]);
    if (FUSE) v = st * v + s1t * tof(skip[roff + base + i]);
    xv[i] = v;
  }
  if (FUSE) {
#pragma unroll
    for (int i = 0; i < 4; i++) x2[roff + base + i] = __float2bfloat16(xv[i]);
  }

  float ls = 0.f, lq = 0.f;
#pragma unroll
  for (int i = 0; i < 4; i++) { ls += xv[i]; lq += xv[i] * xv[i]; }

  __shared__ float ssum[256];
  __shared__ float ssq[256];
  ssum[tid] = ls; ssq[tid] = lq;
  __syncthreads();
  for (int off = 128; off > 0; off >>= 1) {
    if (tid < off) { ssum[tid] += ssum[tid + off]; ssq[tid] += ssq[tid + off]; }
    __syncthreads();
  }
  const float mean = ssum[0] * (1.0f / D_);
  const float var  = ssq[0] * (1.0f / D_) - mean * mean;
  const float rstd = rsqrtf(var + 1e-5f);

#pragma unroll
  for (int i = 0; i < 4; i++) {
    float v = (xv[i] - mean) * rstd * w[base + i] + bias[base + i];
    hout[roff + base + i] = __float2bfloat16(v);
  }
}

// ---------------------------------------------------------------------------
// Generic tiled GEMM: C[M,N] = epilogue( A[M,K] @ B[N,K]^T )
//   EPI 0: v = acc*scale
//   EPI 1: v = gelu_exact((acc + bias[n])*scale) * st        (st = GELU_SCALE)
//   EPI 2: v = ((acc + bias[n])*scale)*st + s1t*resid[m,n]   (final residual)
// Tile 64x64, BK=16, 16x16 threads, 4x4 micro-tile, fp32 accumulate.
// ---------------------------------------------------------------------------
template <int EPI, typename TA, typename TB, typename TC>
__global__ __launch_bounds__(256) void gemm_nt(
    const TA* __restrict__ A, const TB* __restrict__ Bw,
    TC* __restrict__ C, int M, int N, int K, float scale,
    const float* __restrict__ bias, const bf16* __restrict__ resid,
    float st, float s1t) {
  __shared__ float As[16][64];
  __shared__ float Bs[16][64];

  const int tx = threadIdx.x, ty = threadIdx.y;
  const int tid = ty * 16 + tx;
  const int bm = blockIdx.y * 64, bn = blockIdx.x * 64;

  float acc[4][4] = {};

  const int lr = tid >> 2;         // 0..63 : row within tile
  const int lc = (tid & 3) << 2;   // 0,4,8,12 : k-offset
  const TA* Ap = A + (size_t)(bm + lr) * K + lc;
  const TB* Bp = Bw + (size_t)(bn + lr) * K + lc;

  for (int k0 = 0; k0 < K; k0 += 16) {
#pragma unroll
    for (int i = 0; i < 4; i++) As[lc + i][lr] = tof(Ap[k0 + i]);
#pragma unroll
    for (int i = 0; i < 4; i++) Bs[lc + i][lr] = tof(Bp[k0 + i]);
    __syncthreads();
#pragma unroll
    for (int kk = 0; kk < 16; kk++) {
      float av[4], bv[4];
#pragma unroll
      for (int i = 0; i < 4; i++) av[i] = As[kk][ty * 4 + i];
#pragma unroll
      for (int j = 0; j < 4; j++) bv[j] = Bs[kk][tx * 4 + j];
#pragma unroll
      for (int i = 0; i < 4; i++)
#pragma unroll
        for (int j = 0; j < 4; j++) acc[i][j] += av[i] * bv[j];
    }
    __syncthreads();
  }

#pragma unroll
  for (int i = 0; i < 4; i++) {
    const int row = bm + ty * 4 + i;
#pragma unroll
    for (int j = 0; j < 4; j++) {
      const int col = bn + tx * 4 + j;
      float v = acc[i][j];
      if (EPI == 0) {
        v *= scale;
      } else if (EPI == 1) {
        v = (v + bias[col]) * scale;
        v = 0.5f * v * (1.0f + erff(v * 0.70710678118654752f)) * st;
      } else {
        v = (v + bias[col]) * scale;
        v = st * v + s1t * __bfloat162float(resid[(size_t)row * N + col]);
      }
      stf(C, (size_t)row * N + col, v);
    }
  }
}

// ---------------------------------------------------------------------------
// De-interleave qkv: qkv[b,s, d*48 + z*16 + h] -> QKV[z][b][h][s][d]
// ---------------------------------------------------------------------------
__global__ __launch_bounds__(256) void extract_qkv(
    const bf16* __restrict__ qkv, bf16* __restrict__ QKV) {
  size_t i = (size_t)blockIdx.x * 256 + threadIdx.x;  // over 3*B*H*S*DH
  const int d = (int)(i & 63);
  size_t r = i >> 6;
  const int ss = (int)(r & (S_ - 1)); r >>= 11;
  const int hh = (int)(r & (H_ - 1)); r >>= 4;
  const int bb = (int)(r & 1);
  const int z  = (int)(r >> 1);
  const int row = bb * S_ + ss;
  const int col = d * 48 + z * 16 + hh;
  QKV[i] = qkv[(size_t)row * D3_ + col];
}

// ---------------------------------------------------------------------------
// Attention: one block per (query row s, head h, batch b). 256 threads.
// ---------------------------------------------------------------------------
__global__ __launch_bounds__(256) void attn_kernel(
    const bf16* __restrict__ Q, const bf16* __restrict__ K,
    const bf16* __restrict__ V, bf16* __restrict__ att,
    float mm_scale, float sm_scale) {
  const int s = blockIdx.x, h = blockIdx.y, b = blockIdx.z;
  const int bh = b * H_ + h;
  const int tid = threadIdx.x;

  const bf16* Kb = K + (size_t)bh * S_ * DH_;
  const bf16* Vb = V + (size_t)bh * S_ * DH_;
  const bf16* Qrow = Q + ((size_t)bh * S_ + s) * DH_;

  __shared__ float q_s[DH_];
  __shared__ float sc[S_];
  __shared__ float red[256];
  __shared__ float part[256];

  if (tid < DH_) q_s[tid] = __bfloat162float(Qrow[tid]);
  __syncthreads();

  for (int j = tid; j < S_; j += 256) {
    const bf16* Kr = Kb + (size_t)j * DH_;
    float acc = 0.f;
#pragma unroll
    for (int d = 0; d < DH_; d++) acc += q_s[d] * __bfloat162float(Kr[d]);
    sc[j] = acc * mm_scale;
  }
  __syncthreads();

  float m = -1e30f;
  for (int j = tid; j < S_; j += 256) m = fmaxf(m, sc[j]);
  red[tid] = m;
  __syncthreads();
  for (int off = 128; off > 0; off >>= 1) {
    if (tid < off) red[tid] = fmaxf(red[tid], red[tid + off]);
    __syncthreads();
  }
  const float mx = red[0];
  __syncthreads();

  float lsum = 0.f;
  for (int j = tid; j < S_; j += 256) {
    float e = expf(sc[j] - mx);
    sc[j] = e;
    lsum += e;
  }
  red[tid] = lsum;
  __syncthreads();
  for (int off = 128; off > 0; off >>= 1) {
    if (tid < off) red[tid] += red[tid + off];
    __syncthreads();
  }
  const float inv = sm_scale * mm_scale / red[0];

  const int d = tid & 63;
  const int c = tid >> 6;
  float pacc = 0.f;
  const int j0 = c * 512, j1 = j0 + 512;
  for (int j = j0; j < j1; j++)
    pacc += sc[j] * __bfloat162float(Vb[(size_t)j * DH_ + d]);
  part[tid] = pacc;
  __syncthreads();
  if (tid < 64) {
    float tot = part[tid] + part[64 + tid] + part[128 + tid] + part[192 + tid];
    att[((size_t)(b * S_ + s)) * D_ + h * DH_ + tid] = __float2bfloat16(tot * inv);
  }
}

// ---------------------------------------------------------------------------
extern "C" void kernel_launch(void* const* d_in, const int* in_sizes, int n_in,
                              void* d_out, int out_size, void* d_ws, size_t ws_size,
                              hipStream_t stream) {
  const float* x     = (const float*)d_in[0];
  const float* w_qkv = (const float*)d_in[1];
  const float* w_o   = (const float*)d_in[2];
  const float* w1    = (const float*)d_in[3];
  const float* b1    = (const float*)d_in[4];
  const float* w2    = (const float*)d_in[5];
  const float* b2    = (const float*)d_in[6];
  const float* ln1w  = (const float*)d_in[7];
  const float* ln1b  = (const float*)d_in[8];
  const float* ln2w  = (const float*)d_in[9];
  const float* ln2b  = (const float*)d_in[10];
  float* out = (float*)d_out;
  bf16* ws  = (bf16*)d_ws;

  // workspace layout (bf16 elements), with reuse (peak 29,360,128 els = 56 MB)
  bf16* h1       = ws;                 // [0, 4.19M)         LN1 out
  bf16* Qb       = ws + 4194304;       // [4.19M, 8.39M)
  bf16* Kb       = ws + 8388608;       // [8.39M, 12.58M)
  bf16* Vb       = ws + 12582912;      // [12.58M, 16.78M)
  bf16* qkv      = ws + 16777216;      // [16.78M, 29.36M)   raw QKV gemm out
  bf16* att      = ws;                 // reuse h1 (dead after QKV gemm)
  bf16* attn_out = ws + 16777216;      // reuse qkv (dead after extract)
  bf16* x2       = ws + 20971520;
  bf16* h2       = ws + 25165824;
  bf16* g        = ws;                 // [0, 16.78M) overlaps h1+Q/K/V (dead)

  const float MM_SCALE   = (float)pow((double)S_ * S_ * DH_, -1.0 / 6.0);
  const float SM_SCALE   = (float)((double)S_ / sqrt(1.31 * 1.65));
  const float GELU_SCALE = (float)pow(0.588 * 0.675, -0.5);
  const float SQRT_TAU   = (float)sqrt(0.2);
  const float SQRT_1MT   = (float)sqrt(0.8);
  const float qkv_scale  = (float)pow((double)D_ * D3_, -0.25);
  const float o_scale    = (float)pow((double)D_ * D_, -0.25);
  const float w1_scale   = (float)pow((double)D_ * DF_, -0.25);
  const float w2_scale   = (float)pow((double)DF_ * D_, -0.25);

  const dim3 blk2(16, 16);

  // 1. LN1 (fp32 in, bf16 out)
  resid_ln_kernel<false, float, float><<<BS_, 256, 0, stream>>>(
      x, nullptr, ln1w, ln1b, nullptr, h1, 0.f, 0.f);
  // 2. QKV gemm (A bf16, B fp32, C bf16)
  gemm_nt<0, bf16, float, bf16><<<dim3(D3_ / 64, BS_ / 64), blk2, 0, stream>>>(
      h1, w_qkv, qkv, BS_, D3_, D_, qkv_scale, nullptr, nullptr, 0.f, 0.f);
  // 3. de-interleave
  extract_qkv<<<(3 * BS_ * D_) / 256, 256, 0, stream>>>(qkv, Qb);
  // 4. attention
  attn_kernel<<<dim3(S_, H_, B_), 256, 0, stream>>>(Qb, Kb, Vb, att,
                                                    MM_SCALE, SM_SCALE);
  // 5. out-proj
  gemm_nt<0, bf16, float, bf16><<<dim3(D_ / 64, BS_ / 64), blk2, 0, stream>>>(
      att, w_o, attn_out, BS_, D_, D_, o_scale, nullptr, nullptr, 0.f, 0.f);
  // 6. residual + LN2 (a bf16, skip fp32)
  resid_ln_kernel<true, bf16, float><<<BS_, 256, 0, stream>>>(
      attn_out, x, ln2w, ln2b, x2, h2, SQRT_TAU, SQRT_1MT);
  // 7. FFN1 + GELU
  gemm_nt<1, bf16, float, bf16><<<dim3(DF_ / 64, BS_ / 64), blk2, 0, stream>>>(
      h2, w1, g, BS_, DF_, D_, w1_scale, b1, nullptr, GELU_SCALE, 0.f);
  // 8. FFN2 + bias + final residual -> d_out (fp32)
  gemm_nt<2, bf16, float, float><<<dim3(D_ / 64, BS_ / 64), blk2, 0, stream>>>(
      g, w2, out, BS_, D_, DF_, w2_scale, b2, x2, SQRT_TAU, SQRT_1MT);
}

// Round 3
// 2166.108 us; speedup vs baseline: 3.3974x; 3.3974x over previous
//
#include <hip/hip_runtime.h>
#include <hip/hip_bf16.h>
#include <math.h>

typedef __hip_bfloat16 bf16;

#define B_   2
#define S_   2048
#define D_   1024
#define H_   16
#define DH_  64
#define BS_  4096   // B_*S_
#define D3_  3072   // 3*D_
#define DF_  4096   // 4*D_
#define QT_  64     // flash: query-tile rows
#define KT_  64     // flash: kv-tile rows

__device__ __forceinline__ float tof(float v) { return v; }
__device__ __forceinline__ float tof(bf16 v) { return __bfloat162float(v); }
__device__ __forceinline__ void stf(float* p, size_t i, float v) { p[i] = v; }
__device__ __forceinline__ void stf(bf16* p, size_t i, float v) { p[i] = __float2bfloat16(v); }

// ---------------------------------------------------------------------------
// LayerNorm (optionally fused with residual add): one block per row of D_=1024
// ---------------------------------------------------------------------------
template <bool FUSE, typename TA, typename TS>
__global__ __launch_bounds__(256) void resid_ln_kernel(
    const TA* __restrict__ a, const TS* __restrict__ skip,
    const float* __restrict__ w, const float* __restrict__ bias,
    bf16* __restrict__ x2, bf16* __restrict__ hout, float st, float s1t) {
  const int row = blockIdx.x;
  const int tid = threadIdx.x;
  const int base = tid * 4;
  const size_t roff = (size_t)row * D_;

  float xv[4];
#pragma unroll
  for (int i = 0; i < 4; i++) {
    float v = tof(a[roff + base + i]);
    if (FUSE) v = st * v + s1t * tof(skip[roff + base + i]);
    xv[i] = v;
  }
  if (FUSE) {
#pragma unroll
    for (int i = 0; i < 4; i++) x2[roff + base + i] = __float2bfloat16(xv[i]);
  }

  float ls = 0.f, lq = 0.f;
#pragma unroll
  for (int i = 0; i < 4; i++) { ls += xv[i]; lq += xv[i] * xv[i]; }

  __shared__ float ssum[256];
  __shared__ float ssq[256];
  ssum[tid] = ls; ssq[tid] = lq;
  __syncthreads();
  for (int off = 128; off > 0; off >>= 1) {
    if (tid < off) { ssum[tid] += ssum[tid + off]; ssq[tid] += ssq[tid + off]; }
    __syncthreads();
  }
  const float mean = ssum[0] * (1.0f / D_);
  const float var  = ssq[0] * (1.0f / D_) - mean * mean;
  const float rstd = rsqrtf(var + 1e-5f);

#pragma unroll
  for (int i = 0; i < 4; i++) {
    float v = (xv[i] - mean) * rstd * w[base + i] + bias[base + i];
    hout[roff + base + i] = __float2bfloat16(v);
  }
}

// ---------------------------------------------------------------------------
// Generic tiled GEMM: C[M,N] = epilogue( A[M,K] @ B[N,K]^T )
// ---------------------------------------------------------------------------
template <int EPI, typename TA, typename TB, typename TC>
__global__ __launch_bounds__(256) void gemm_nt(
    const TA* __restrict__ A, const TB* __restrict__ Bw,
    TC* __restrict__ C, int M, int N, int K, float scale,
    const float* __restrict__ bias, const bf16* __restrict__ resid,
    float st, float s1t) {
  __shared__ float As[16][64];
  __shared__ float Bs[16][64];

  const int tx = threadIdx.x, ty = threadIdx.y;
  const int tid = ty * 16 + tx;
  const int bm = blockIdx.y * 64, bn = blockIdx.x * 64;

  float acc[4][4] = {};

  const int lr = tid >> 2;
  const int lc = (tid & 3) << 2;
  const TA* Ap = A + (size_t)(bm + lr) * K + lc;
  const TB* Bp = Bw + (size_t)(bn + lr) * K + lc;

  for (int k0 = 0; k0 < K; k0 += 16) {
#pragma unroll
    for (int i = 0; i < 4; i++) As[lc + i][lr] = tof(Ap[k0 + i]);
#pragma unroll
    for (int i = 0; i < 4; i++) Bs[lc + i][lr] = tof(Bp[k0 + i]);
    __syncthreads();
#pragma unroll
    for (int kk = 0; kk < 16; kk++) {
      float av[4], bv[4];
#pragma unroll
      for (int i = 0; i < 4; i++) av[i] = As[kk][ty * 4 + i];
#pragma unroll
      for (int j = 0; j < 4; j++) bv[j] = Bs[kk][tx * 4 + j];
#pragma unroll
      for (int i = 0; i < 4; i++)
#pragma unroll
        for (int j = 0; j < 4; j++) acc[i][j] += av[i] * bv[j];
    }
    __syncthreads();
  }

#pragma unroll
  for (int i = 0; i < 4; i++) {
    const int row = bm + ty * 4 + i;
#pragma unroll
    for (int j = 0; j < 4; j++) {
      const int col = bn + tx * 4 + j;
      float v = acc[i][j];
      if (EPI == 0) {
        v *= scale;
      } else if (EPI == 1) {
        v = (v + bias[col]) * scale;
        v = 0.5f * v * (1.0f + erff(v * 0.70710678118654752f)) * st;
      } else {
        v = (v + bias[col]) * scale;
        v = st * v + s1t * __bfloat162float(resid[(size_t)row * N + col]);
      }
      stf(C, (size_t)row * N + col, v);
    }
  }
}

// ---------------------------------------------------------------------------
// De-interleave qkv: qkv[b,s, d*48 + z*16 + h] -> QKV[z][b][h][s][d]
// ---------------------------------------------------------------------------
__global__ __launch_bounds__(256) void extract_qkv(
    const bf16* __restrict__ qkv, bf16* __restrict__ QKV) {
  size_t i = (size_t)blockIdx.x * 256 + threadIdx.x;
  const int d = (int)(i & 63);
  size_t r = i >> 6;
  const int ss = (int)(r & (S_ - 1)); r >>= 11;
  const int hh = (int)(r & (H_ - 1)); r >>= 4;
  const int bb = (int)(r & 1);
  const int z  = (int)(r >> 1);
  const int row = bb * S_ + ss;
  const int col = d * 48 + z * 16 + hh;
  QKV[i] = qkv[(size_t)row * D3_ + col];
}

// ---------------------------------------------------------------------------
// Flash attention: one block per (64-row Q-tile, head h, batch b), 256 thr.
// Online softmax; S-tile and P@V as 4x4-microtile register GEMMs from LDS.
// Q pre-scaled by mm_scale; final scale = sm_scale*mm_scale / l.
// ---------------------------------------------------------------------------
__global__ __launch_bounds__(256) void flash_attn_kernel(
    const bf16* __restrict__ Q, const bf16* __restrict__ K,
    const bf16* __restrict__ V, bf16* __restrict__ att,
    float mm_scale, float out_scale) {
  const int qb = blockIdx.x * QT_;
  const int h = blockIdx.y, b = blockIdx.z;
  const int bh = b * H_ + h;
  const int tx = threadIdx.x, ty = threadIdx.y;
  const int tid = ty * 16 + tx;

  __shared__ float Qs[DH_][QT_ + 1];   // Qs[d][r] = mm_scale * Q[r][d]
  __shared__ float Ks[DH_][KT_ + 1];   // Ks[d][j] = K[j][d]
  __shared__ float Ps[KT_][QT_ + 1];   // Ps[j][r] = P[r][j]
  __shared__ float Vs[KT_][DH_];       // Vs[j][d] = V[j][d]
  __shared__ float red[16][QT_ + 1];
  __shared__ float m_s[QT_], l_s[QT_], alpha_s[QT_];

  const bf16* Qbase = Q + (size_t)bh * S_ * DH_;
  const bf16* Kbase = K + (size_t)bh * S_ * DH_;
  const bf16* Vbase = V + (size_t)bh * S_ * DH_;

  // stage Q tile, transposed + pre-scaled
  {
    const int r = tid >> 2;
    const int d0 = (tid & 3) * 16;
    const uint4* src = (const uint4*)(Qbase + (size_t)(qb + r) * DH_ + d0);
#pragma unroll
    for (int v = 0; v < 2; v++) {
      uint4 u = src[v];
      uint w[4] = {u.x, u.y, u.z, u.w};
#pragma unroll
      for (int e = 0; e < 4; e++) {
        Qs[d0 + v * 8 + e * 2 + 0][r] = mm_scale * __uint_as_float(w[e] << 16);
        Qs[d0 + v * 8 + e * 2 + 1][r] = mm_scale * __uint_as_float(w[e] & 0xffff0000u);
      }
    }
  }
  if (tid < QT_) { m_s[tid] = -1e30f; l_s[tid] = 0.f; }

  float o[4][4] = {};

  for (int t = 0; t < S_ / KT_; t++) {
    __syncthreads();  // Q ready (t=0); Ks/Vs/Ps no longer read (t>0)
    // stage K (transposed) and V (natural)
    {
      const int r = tid >> 2;
      const int d0 = (tid & 3) * 16;
      const uint4* ks = (const uint4*)(Kbase + (size_t)(t * KT_ + r) * DH_ + d0);
#pragma unroll
      for (int v = 0; v < 2; v++) {
        uint4 u = ks[v];
        uint w[4] = {u.x, u.y, u.z, u.w};
#pragma unroll
        for (int e = 0; e < 4; e++) {
          Ks[d0 + v * 8 + e * 2 + 0][r] = __uint_as_float(w[e] << 16);
          Ks[d0 + v * 8 + e * 2 + 1][r] = __uint_as_float(w[e] & 0xffff0000u);
        }
      }
      const uint4* vs = (const uint4*)(Vbase + (size_t)(t * KT_ + r) * DH_ + d0);
#pragma unroll
      for (int v = 0; v < 2; v++) {
        uint4 u = vs[v];
        uint w[4] = {u.x, u.y, u.z, u.w};
#pragma unroll
        for (int e = 0; e < 4; e++) {
          Vs[r][d0 + v * 8 + e * 2 + 0] = __uint_as_float(w[e] << 16);
          Vs[r][d0 + v * 8 + e * 2 + 1] = __uint_as_float(w[e] & 0xffff0000u);
        }
      }
    }
    __syncthreads();

    // S tile: rows ty*4+i, cols tx*4+j (already scaled via Q)
    float s[4][4] = {};
#pragma unroll 8
    for (int kk = 0; kk < DH_; kk++) {
      float qv[4], kv[4];
#pragma unroll
      for (int i = 0; i < 4; i++) qv[i] = Qs[kk][ty * 4 + i];
#pragma unroll
      for (int j = 0; j < 4; j++) kv[j] = Ks[kk][tx * 4 + j];
#pragma unroll
      for (int i = 0; i < 4; i++)
#pragma unroll
        for (int j = 0; j < 4; j++) s[i][j] += qv[i] * kv[j];
    }
    // partial row max
#pragma unroll
    for (int i = 0; i < 4; i++) {
      red[tx][ty * 4 + i] =
          fmaxf(fmaxf(s[i][0], s[i][1]), fmaxf(s[i][2], s[i][3]));
    }
    __syncthreads();
    if (tid < QT_) {
      float rm = red[0][tid];
#pragma unroll
      for (int t2 = 1; t2 < 16; t2++) rm = fmaxf(rm, red[t2][tid]);
      const float mo = m_s[tid];
      const float mn = fmaxf(mo, rm);
      m_s[tid] = mn;
      alpha_s[tid] = __expf(mo - mn);
    }
    __syncthreads();
    // P = exp(s - m); rescale O; partial row sums; write Ps
#pragma unroll
    for (int i = 0; i < 4; i++) {
      const int r = ty * 4 + i;
      const float mn = m_s[r];
      const float a = alpha_s[r];
      float rs = 0.f;
#pragma unroll
      for (int j = 0; j < 4; j++) {
        const float p = __expf(s[i][j] - mn);
        Ps[tx * 4 + j][r] = p;
        rs += p;
        o[i][j] *= a;
      }
      red[tx][r] = rs;
    }
    __syncthreads();
    if (tid < QT_) {
      float rs = 0.f;
#pragma unroll
      for (int t2 = 0; t2 < 16; t2++) rs += red[t2][tid];
      l_s[tid] = alpha_s[tid] * l_s[tid] + rs;
    }
    // O += P @ V
#pragma unroll 8
    for (int kk = 0; kk < KT_; kk++) {
      float pv[4], vv[4];
#pragma unroll
      for (int i = 0; i < 4; i++) pv[i] = Ps[kk][ty * 4 + i];
#pragma unroll
      for (int j = 0; j < 4; j++) vv[j] = Vs[kk][tx * 4 + j];
#pragma unroll
      for (int i = 0; i < 4; i++)
#pragma unroll
        for (int j = 0; j < 4; j++) o[i][j] += pv[i] * vv[j];
    }
  }
  __syncthreads();  // final l_s visible

#pragma unroll
  for (int i = 0; i < 4; i++) {
    const int r = ty * 4 + i;
    const float sc = out_scale / l_s[r];
    const size_t base = ((size_t)(b * S_ + qb + r)) * D_ + h * DH_ + tx * 4;
#pragma unroll
    for (int j = 0; j < 4; j++)
      att[base + j] = __float2bfloat16(o[i][j] * sc);
  }
}

// ---------------------------------------------------------------------------
extern "C" void kernel_launch(void* const* d_in, const int* in_sizes, int n_in,
                              void* d_out, int out_size, void* d_ws, size_t ws_size,
                              hipStream_t stream) {
  const float* x     = (const float*)d_in[0];
  const float* w_qkv = (const float*)d_in[1];
  const float* w_o   = (const float*)d_in[2];
  const float* w1    = (const float*)d_in[3];
  const float* b1    = (const float*)d_in[4];
  const float* w2    = (const float*)d_in[5];
  const float* b2    = (const float*)d_in[6];
  const float* ln2w  = (const float*)d_in[9];
  const float* ln2b  = (const float*)d_in[10];
  const float* ln1w  = (const float*)d_in[7];
  const float* ln1b  = (const float*)d_in[8];
  float* out = (float*)d_out;
  bf16* ws  = (bf16*)d_ws;

  // workspace layout (bf16 elements), with reuse (peak 29,360,128 els = 56 MB)
  bf16* h1       = ws;                 // LN1 out
  bf16* Qb       = ws + 4194304;
  bf16* Kb       = ws + 8388608;
  bf16* Vb       = ws + 12582912;
  bf16* qkv      = ws + 16777216;      // raw QKV gemm out
  bf16* att      = ws;                 // reuse h1 (dead after QKV gemm)
  bf16* attn_out = ws + 16777216;      // reuse qkv (dead after extract)
  bf16* x2       = ws + 20971520;
  bf16* h2       = ws + 25165824;
  bf16* g        = ws;                 // overlaps h1+Q/K/V (dead)

  const float MM_SCALE   = (float)pow((double)S_ * S_ * DH_, -1.0 / 6.0);
  const float SM_SCALE   = (float)((double)S_ / sqrt(1.31 * 1.65));
  const float GELU_SCALE = (float)pow(0.588 * 0.675, -0.5);
  const float SQRT_TAU   = (float)sqrt(0.2);
  const float SQRT_1MT   = (float)sqrt(0.8);
  const float qkv_scale  = (float)pow((double)D_ * D3_, -0.25);
  const float o_scale    = (float)pow((double)D_ * D_, -0.25);
  const float w1_scale   = (float)pow((double)D_ * DF_, -0.25);
  const float w2_scale   = (float)pow((double)DF_ * D_, -0.25);

  const dim3 blk2(16, 16);

  // 1. LN1
  resid_ln_kernel<false, float, float><<<BS_, 256, 0, stream>>>(
      x, nullptr, ln1w, ln1b, nullptr, h1, 0.f, 0.f);
  // 2. QKV gemm
  gemm_nt<0, bf16, float, bf16><<<dim3(D3_ / 64, BS_ / 64), blk2, 0, stream>>>(
      h1, w_qkv, qkv, BS_, D3_, D_, qkv_scale, nullptr, nullptr, 0.f, 0.f);
  // 3. de-interleave
  extract_qkv<<<(3 * BS_ * D_) / 256, 256, 0, stream>>>(qkv, Qb);
  // 4. flash attention
  flash_attn_kernel<<<dim3(S_ / QT_, H_, B_), blk2, 0, stream>>>(
      Qb, Kb, Vb, att, MM_SCALE, SM_SCALE * MM_SCALE);
  // 5. out-proj
  gemm_nt<0, bf16, float, bf16><<<dim3(D_ / 64, BS_ / 64), blk2, 0, stream>>>(
      att, w_o, attn_out, BS_, D_, D_, o_scale, nullptr, nullptr, 0.f, 0.f);
  // 6. residual + LN2
  resid_ln_kernel<true, bf16, float><<<BS_, 256, 0, stream>>>(
      attn_out, x, ln2w, ln2b, x2, h2, SQRT_TAU, SQRT_1MT);
  // 7. FFN1 + GELU
  gemm_nt<1, bf16, float, bf16><<<dim3(DF_ / 64, BS_ / 64), blk2, 0, stream>>>(
      h2, w1, g, BS_, DF_, D_, w1_scale, b1, nullptr, GELU_SCALE, 0.f);
  // 8. FFN2 + bias + final residual -> d_out (fp32)
  gemm_nt<2, bf16, float, float><<<dim3(D_ / 64, BS_ / 64), blk2, 0, stream>>>(
      g, w2, out, BS_, D_, DF_, w2_scale, b2, x2, SQRT_TAU, SQRT_1MT);
}

// Round 4
// 998.738 us; speedup vs baseline: 7.3685x; 2.1688x over previous
//
#include <hip/hip_runtime.h>
#include <hip/hip_bf16.h>
#include <math.h>

typedef __hip_bfloat16 bf16;
typedef __attribute__((ext_vector_type(8))) short short8;
typedef __attribute__((ext_vector_type(4))) float floatx4;

#define B_   2
#define S_   2048
#define D_   1024
#define H_   16
#define DH_  64
#define BS_  4096   // B_*S_
#define D3_  3072   // 3*D_
#define DF_  4096   // 4*D_
#define QT_  64     // flash: query-tile rows
#define KT_  64     // flash: kv-tile rows

__device__ __forceinline__ float tof(float v) { return v; }
__device__ __forceinline__ float tof(bf16 v) { return __bfloat162float(v); }
__device__ __forceinline__ void stf(float* p, size_t i, float v) { p[i] = v; }
__device__ __forceinline__ void stf(bf16* p, size_t i, float v) { p[i] = __float2bfloat16(v); }

// ---------------------------------------------------------------------------
// fp32 -> bf16 weight conversion (vectorized x4)
// ---------------------------------------------------------------------------
__global__ __launch_bounds__(256) void cvt_f32_bf16(
    const float* __restrict__ in, bf16* __restrict__ out, int n4) {
  int i = blockIdx.x * 256 + threadIdx.x;
  if (i >= n4) return;
  float4 v = ((const float4*)in)[i];
  bf16 o[4] = {__float2bfloat16(v.x), __float2bfloat16(v.y),
               __float2bfloat16(v.z), __float2bfloat16(v.w)};
  ((ulong1*)out)[i] = *(ulong1*)o;
}

// ---------------------------------------------------------------------------
// LayerNorm (optionally fused with residual add): one block per row of D_=1024
// ---------------------------------------------------------------------------
template <bool FUSE, typename TA, typename TS>
__global__ __launch_bounds__(256) void resid_ln_kernel(
    const TA* __restrict__ a, const TS* __restrict__ skip,
    const float* __restrict__ w, const float* __restrict__ bias,
    bf16* __restrict__ x2, bf16* __restrict__ hout, float st, float s1t) {
  const int row = blockIdx.x;
  const int tid = threadIdx.x;
  const int base = tid * 4;
  const size_t roff = (size_t)row * D_;

  float xv[4];
#pragma unroll
  for (int i = 0; i < 4; i++) {
    float v = tof(a[roff + base + i]);
    if (FUSE) v = st * v + s1t * tof(skip[roff + base + i]);
    xv[i] = v;
  }
  if (FUSE) {
#pragma unroll
    for (int i = 0; i < 4; i++) x2[roff + base + i] = __float2bfloat16(xv[i]);
  }

  float ls = 0.f, lq = 0.f;
#pragma unroll
  for (int i = 0; i < 4; i++) { ls += xv[i]; lq += xv[i] * xv[i]; }

  __shared__ float ssum[256];
  __shared__ float ssq[256];
  ssum[tid] = ls; ssq[tid] = lq;
  __syncthreads();
  for (int off = 128; off > 0; off >>= 1) {
    if (tid < off) { ssum[tid] += ssum[tid + off]; ssq[tid] += ssq[tid + off]; }
    __syncthreads();
  }
  const float mean = ssum[0] * (1.0f / D_);
  const float var  = ssq[0] * (1.0f / D_) - mean * mean;
  const float rstd = rsqrtf(var + 1e-5f);

#pragma unroll
  for (int i = 0; i < 4; i++) {
    float v = (xv[i] - mean) * rstd * w[base + i] + bias[base + i];
    hout[roff + base + i] = __float2bfloat16(v);
  }
}

// ---------------------------------------------------------------------------
// MFMA GEMM: C[M,N] = epilogue( A[M,K] @ Bw[N,K]^T ), both bf16.
// 128x128 tile, BK=32, 4 waves 2x2, each wave 4x4 frags of 16x16x32.
// A-frag layout: A[m=lane&15][k=quad*8+j]; C/D: col=lane&15,row=quad*4+reg.
//   EPI 0: v = acc*scale
//   EPI 1: v = gelu_exact((acc + bias[n])*scale) * st
//   EPI 2: v = ((acc + bias[n])*scale)*st + s1t*resid[m,n]
// ---------------------------------------------------------------------------
template <int EPI, typename TC>
__global__ __launch_bounds__(256) void gemm_mfma(
    const bf16* __restrict__ A, const bf16* __restrict__ Bw,
    TC* __restrict__ C, int M, int N, int K, float scale,
    const float* __restrict__ bias, const bf16* __restrict__ resid,
    float st, float s1t) {
  __shared__ __align__(16) bf16 As[128][32];
  __shared__ __align__(16) bf16 Bs[128][32];

  const int tid = threadIdx.x;
  const int lane = tid & 63;
  const int w = tid >> 6;
  const int wm = (w >> 1) * 64;
  const int wn = (w & 1) * 64;
  const int quad = lane >> 4;
  const int l16 = lane & 15;
  const int bm = blockIdx.y * 128, bn = blockIdx.x * 128;

  floatx4 acc[4][4];
#pragma unroll
  for (int i = 0; i < 4; i++)
#pragma unroll
    for (int j = 0; j < 4; j++) acc[i][j] = {0.f, 0.f, 0.f, 0.f};

  // staging: 512 16-byte chunks per tile; thread t does chunks t and t+256
  const int r0 = tid >> 2, o0 = (tid & 3) * 8;
  const int r1 = (tid + 256) >> 2, o1 = ((tid + 256) & 3) * 8;
  const bf16* Ap0 = A + (size_t)(bm + r0) * K + o0;
  const bf16* Ap1 = A + (size_t)(bm + r1) * K + o1;
  const bf16* Bp0 = Bw + (size_t)(bn + r0) * K + o0;
  const bf16* Bp1 = Bw + (size_t)(bn + r1) * K + o1;

  for (int k0 = 0; k0 < K; k0 += 32) {
    __syncthreads();
    ((uint4*)As)[tid]       = *(const uint4*)(Ap0 + k0);
    ((uint4*)As)[tid + 256] = *(const uint4*)(Ap1 + k0);
    ((uint4*)Bs)[tid]       = *(const uint4*)(Bp0 + k0);
    ((uint4*)Bs)[tid + 256] = *(const uint4*)(Bp1 + k0);
    __syncthreads();

    short8 af[4], bf[4];
#pragma unroll
    for (int f = 0; f < 4; f++) {
      af[f] = *(const short8*)&As[wm + f * 16 + l16][quad * 8];
      bf[f] = *(const short8*)&Bs[wn + f * 16 + l16][quad * 8];
    }
#pragma unroll
    for (int fi = 0; fi < 4; fi++)
#pragma unroll
      for (int fj = 0; fj < 4; fj++)
        acc[fi][fj] = __builtin_amdgcn_mfma_f32_16x16x32_bf16(
            af[fi], bf[fj], acc[fi][fj], 0, 0, 0);
  }

  // epilogue: frag (fi,fj), lane holds col=l16, rows quad*4+r
#pragma unroll
  for (int fi = 0; fi < 4; fi++) {
#pragma unroll
    for (int fj = 0; fj < 4; fj++) {
      const int col = bn + wn + fj * 16 + l16;
#pragma unroll
      for (int r = 0; r < 4; r++) {
        const int row = bm + wm + fi * 16 + quad * 4 + r;
        float v = acc[fi][fj][r];
        if (EPI == 0) {
          v *= scale;
        } else if (EPI == 1) {
          v = (v + bias[col]) * scale;
          v = 0.5f * v * (1.0f + erff(v * 0.70710678118654752f)) * st;
        } else {
          v = (v + bias[col]) * scale;
          v = st * v + s1t * __bfloat162float(resid[(size_t)row * N + col]);
        }
        stf(C, (size_t)row * N + col, v);
      }
    }
  }
}

// ---------------------------------------------------------------------------
// De-interleave qkv: qkv[b,s, d*48 + z*16 + h] -> QKV[z][b][h][s][d]
// ---------------------------------------------------------------------------
__global__ __launch_bounds__(256) void extract_qkv(
    const bf16* __restrict__ qkv, bf16* __restrict__ QKV) {
  size_t i = (size_t)blockIdx.x * 256 + threadIdx.x;
  const int d = (int)(i & 63);
  size_t r = i >> 6;
  const int ss = (int)(r & (S_ - 1)); r >>= 11;
  const int hh = (int)(r & (H_ - 1)); r >>= 4;
  const int bb = (int)(r & 1);
  const int z  = (int)(r >> 1);
  const int row = bb * S_ + ss;
  const int col = d * 48 + z * 16 + hh;
  QKV[i] = qkv[(size_t)row * D3_ + col];
}

// ---------------------------------------------------------------------------
// Flash attention: one block per (64-row Q-tile, head h, batch b), 256 thr.
// ---------------------------------------------------------------------------
__global__ __launch_bounds__(256) void flash_attn_kernel(
    const bf16* __restrict__ Q, const bf16* __restrict__ K,
    const bf16* __restrict__ V, bf16* __restrict__ att,
    float mm_scale, float out_scale) {
  const int qb = blockIdx.x * QT_;
  const int h = blockIdx.y, b = blockIdx.z;
  const int bh = b * H_ + h;
  const int tx = threadIdx.x, ty = threadIdx.y;
  const int tid = ty * 16 + tx;

  __shared__ float Qs[DH_][QT_ + 1];
  __shared__ float Ks[DH_][KT_ + 1];
  __shared__ float Ps[KT_][QT_ + 1];
  __shared__ float Vs[KT_][DH_];
  __shared__ float red[16][QT_ + 1];
  __shared__ float m_s[QT_], l_s[QT_], alpha_s[QT_];

  const bf16* Qbase = Q + (size_t)bh * S_ * DH_;
  const bf16* Kbase = K + (size_t)bh * S_ * DH_;
  const bf16* Vbase = V + (size_t)bh * S_ * DH_;

  {
    const int r = tid >> 2;
    const int d0 = (tid & 3) * 16;
    const uint4* src = (const uint4*)(Qbase + (size_t)(qb + r) * DH_ + d0);
#pragma unroll
    for (int v = 0; v < 2; v++) {
      uint4 u = src[v];
      uint w[4] = {u.x, u.y, u.z, u.w};
#pragma unroll
      for (int e = 0; e < 4; e++) {
        Qs[d0 + v * 8 + e * 2 + 0][r] = mm_scale * __uint_as_float(w[e] << 16);
        Qs[d0 + v * 8 + e * 2 + 1][r] = mm_scale * __uint_as_float(w[e] & 0xffff0000u);
      }
    }
  }
  if (tid < QT_) { m_s[tid] = -1e30f; l_s[tid] = 0.f; }

  float o[4][4] = {};

  for (int t = 0; t < S_ / KT_; t++) {
    __syncthreads();
    {
      const int r = tid >> 2;
      const int d0 = (tid & 3) * 16;
      const uint4* ks = (const uint4*)(Kbase + (size_t)(t * KT_ + r) * DH_ + d0);
#pragma unroll
      for (int v = 0; v < 2; v++) {
        uint4 u = ks[v];
        uint w[4] = {u.x, u.y, u.z, u.w};
#pragma unroll
        for (int e = 0; e < 4; e++) {
          Ks[d0 + v * 8 + e * 2 + 0][r] = __uint_as_float(w[e] << 16);
          Ks[d0 + v * 8 + e * 2 + 1][r] = __uint_as_float(w[e] & 0xffff0000u);
        }
      }
      const uint4* vs = (const uint4*)(Vbase + (size_t)(t * KT_ + r) * DH_ + d0);
#pragma unroll
      for (int v = 0; v < 2; v++) {
        uint4 u = vs[v];
        uint w[4] = {u.x, u.y, u.z, u.w};
#pragma unroll
        for (int e = 0; e < 4; e++) {
          Vs[r][d0 + v * 8 + e * 2 + 0] = __uint_as_float(w[e] << 16);
          Vs[r][d0 + v * 8 + e * 2 + 1] = __uint_as_float(w[e] & 0xffff0000u);
        }
      }
    }
    __syncthreads();

    float s[4][4] = {};
#pragma unroll 8
    for (int kk = 0; kk < DH_; kk++) {
      float qv[4], kv[4];
#pragma unroll
      for (int i = 0; i < 4; i++) qv[i] = Qs[kk][ty * 4 + i];
#pragma unroll
      for (int j = 0; j < 4; j++) kv[j] = Ks[kk][tx * 4 + j];
#pragma unroll
      for (int i = 0; i < 4; i++)
#pragma unroll
        for (int j = 0; j < 4; j++) s[i][j] += qv[i] * kv[j];
    }
#pragma unroll
    for (int i = 0; i < 4; i++) {
      red[tx][ty * 4 + i] =
          fmaxf(fmaxf(s[i][0], s[i][1]), fmaxf(s[i][2], s[i][3]));
    }
    __syncthreads();
    if (tid < QT_) {
      float rm = red[0][tid];
#pragma unroll
      for (int t2 = 1; t2 < 16; t2++) rm = fmaxf(rm, red[t2][tid]);
      const float mo = m_s[tid];
      const float mn = fmaxf(mo, rm);
      m_s[tid] = mn;
      alpha_s[tid] = __expf(mo - mn);
    }
    __syncthreads();
#pragma unroll
    for (int i = 0; i < 4; i++) {
      const int r = ty * 4 + i;
      const float mn = m_s[r];
      const float a = alpha_s[r];
      float rs = 0.f;
#pragma unroll
      for (int j = 0; j < 4; j++) {
        const float p = __expf(s[i][j] - mn);
        Ps[tx * 4 + j][r] = p;
        rs += p;
        o[i][j] *= a;
      }
      red[tx][r] = rs;
    }
    __syncthreads();
    if (tid < QT_) {
      float rs = 0.f;
#pragma unroll
      for (int t2 = 0; t2 < 16; t2++) rs += red[t2][tid];
      l_s[tid] = alpha_s[tid] * l_s[tid] + rs;
    }
#pragma unroll 8
    for (int kk = 0; kk < KT_; kk++) {
      float pv[4], vv[4];
#pragma unroll
      for (int i = 0; i < 4; i++) pv[i] = Ps[kk][ty * 4 + i];
#pragma unroll
      for (int j = 0; j < 4; j++) vv[j] = Vs[kk][tx * 4 + j];
#pragma unroll
      for (int i = 0; i < 4; i++)
#pragma unroll
        for (int j = 0; j < 4; j++) o[i][j] += pv[i] * vv[j];
    }
  }
  __syncthreads();

#pragma unroll
  for (int i = 0; i < 4; i++) {
    const int r = ty * 4 + i;
    const float sc = out_scale / l_s[r];
    const size_t base = ((size_t)(b * S_ + qb + r)) * D_ + h * DH_ + tx * 4;
#pragma unroll
    for (int j = 0; j < 4; j++)
      att[base + j] = __float2bfloat16(o[i][j] * sc);
  }
}

// ---------------------------------------------------------------------------
extern "C" void kernel_launch(void* const* d_in, const int* in_sizes, int n_in,
                              void* d_out, int out_size, void* d_ws, size_t ws_size,
                              hipStream_t stream) {
  const float* x     = (const float*)d_in[0];
  const float* w_qkv = (const float*)d_in[1];
  const float* w_o   = (const float*)d_in[2];
  const float* w1    = (const float*)d_in[3];
  const float* b1    = (const float*)d_in[4];
  const float* w2    = (const float*)d_in[5];
  const float* b2    = (const float*)d_in[6];
  const float* ln1w  = (const float*)d_in[7];
  const float* ln1b  = (const float*)d_in[8];
  const float* ln2w  = (const float*)d_in[9];
  const float* ln2b  = (const float*)d_in[10];
  float* out = (float*)d_out;
  bf16* ws  = (bf16*)d_ws;

  // workspace layout (bf16 elements), with reuse (peak 29,360,128 els = 58.7 MB)
  // Liveness-audited: weight-convert buffers live only between their cvt and
  // their gemm, placed in regions dead at that point in the stream order.
  bf16* h1       = ws;                 // [0,4.19M)     LN1 out; dead after QKV gemm
  bf16* Qb       = ws + 4194304;       // [4.19M,8.39M)
  bf16* Kb       = ws + 8388608;
  bf16* Vb       = ws + 12582912;      // Q/K/V dead after flash
  bf16* qkv      = ws + 16777216;      // [16.78M,29.36M); dead after extract
  bf16* att      = ws;                 // = h1 region
  bf16* attn_out = ws + 16777216;      // dead after LN2
  bf16* x2       = ws + 20971520;
  bf16* h2       = ws + 25165824;
  bf16* g        = ws;                 // [0,16.78M): h1+Q/K/V regions (dead)
  bf16* wqb      = ws + 4194304;       // 3.15M els; overwritten by extract (ok)
  bf16* wob      = ws + 4194304;       // 1.05M els; Q region, dead after flash
  bf16* w1b      = ws + 16777216;      // 4.19M els; attn_out region, dead
  bf16* w2b      = ws + 16777216;      // 4.19M els; w1b dead after FFN1

  const float MM_SCALE   = (float)pow((double)S_ * S_ * DH_, -1.0 / 6.0);
  const float SM_SCALE   = (float)((double)S_ / sqrt(1.31 * 1.65));
  const float GELU_SCALE = (float)pow(0.588 * 0.675, -0.5);
  const float SQRT_TAU   = (float)sqrt(0.2);
  const float SQRT_1MT   = (float)sqrt(0.8);
  const float qkv_scale  = (float)pow((double)D_ * D3_, -0.25);
  const float o_scale    = (float)pow((double)D_ * D_, -0.25);
  const float w1_scale   = (float)pow((double)D_ * DF_, -0.25);
  const float w2_scale   = (float)pow((double)DF_ * D_, -0.25);

  // 1. LN1
  resid_ln_kernel<false, float, float><<<BS_, 256, 0, stream>>>(
      x, nullptr, ln1w, ln1b, nullptr, h1, 0.f, 0.f);
  // 2. convert w_qkv; QKV gemm
  cvt_f32_bf16<<<(D3_ * D_ / 4 + 255) / 256, 256, 0, stream>>>(w_qkv, wqb, D3_ * D_ / 4);
  gemm_mfma<0, bf16><<<dim3(D3_ / 128, BS_ / 128), 256, 0, stream>>>(
      h1, wqb, qkv, BS_, D3_, D_, qkv_scale, nullptr, nullptr, 0.f, 0.f);
  // 3. de-interleave
  extract_qkv<<<(3 * BS_ * D_) / 256, 256, 0, stream>>>(qkv, Qb);
  // 4. flash attention
  flash_attn_kernel<<<dim3(S_ / QT_, H_, B_), dim3(16, 16), 0, stream>>>(
      Qb, Kb, Vb, att, MM_SCALE, SM_SCALE * MM_SCALE);
  // 5. convert w_o; out-proj
  cvt_f32_bf16<<<(D_ * D_ / 4 + 255) / 256, 256, 0, stream>>>(w_o, wob, D_ * D_ / 4);
  gemm_mfma<0, bf16><<<dim3(D_ / 128, BS_ / 128), 256, 0, stream>>>(
      att, wob, attn_out, BS_, D_, D_, o_scale, nullptr, nullptr, 0.f, 0.f);
  // 6. residual + LN2
  resid_ln_kernel<true, bf16, float><<<BS_, 256, 0, stream>>>(
      attn_out, x, ln2w, ln2b, x2, h2, SQRT_TAU, SQRT_1MT);
  // 7. convert w1; FFN1 + GELU
  cvt_f32_bf16<<<(DF_ * D_ / 4 + 255) / 256, 256, 0, stream>>>(w1, w1b, DF_ * D_ / 4);
  gemm_mfma<1, bf16><<<dim3(DF_ / 128, BS_ / 128), 256, 0, stream>>>(
      h2, w1b, g, BS_, DF_, D_, w1_scale, b1, nullptr, GELU_SCALE, 0.f);
  // 8. convert w2; FFN2 + bias + final residual -> d_out (fp32)
  cvt_f32_bf16<<<(D_ * DF_ / 4 + 255) / 256, 256, 0, stream>>>(w2, w2b, D_ * DF_ / 4);
  gemm_mfma<2, float><<<dim3(D_ / 128, BS_ / 128), 256, 0, stream>>>(
      g, w2b, out, BS_, D_, DF_, w2_scale, b2, x2, SQRT_TAU, SQRT_1MT);
}

// Round 5
// 516.716 us; speedup vs baseline: 14.2423x; 1.9329x over previous
//
#include <hip/hip_runtime.h>
#include <hip/hip_bf16.h>
#include <math.h>

typedef __hip_bfloat16 bf16;
typedef __attribute__((ext_vector_type(8))) short short8;
typedef __attribute__((ext_vector_type(4))) float floatx4;

#define B_   2
#define S_   2048
#define D_   1024
#define H_   16
#define DH_  64
#define BS_  4096   // B_*S_
#define D3_  3072   // 3*D_
#define DF_  4096   // 4*D_

__device__ __forceinline__ float tof(float v) { return v; }
__device__ __forceinline__ float tof(bf16 v) { return __bfloat162float(v); }
__device__ __forceinline__ void stf(float* p, size_t i, float v) { p[i] = v; }
__device__ __forceinline__ void stf(bf16* p, size_t i, float v) { p[i] = __float2bfloat16(v); }

// ---------------------------------------------------------------------------
// fp32 -> bf16 weight conversion (vectorized x4)
// ---------------------------------------------------------------------------
__global__ __launch_bounds__(256) void cvt_f32_bf16(
    const float* __restrict__ in, bf16* __restrict__ out, int n4) {
  int i = blockIdx.x * 256 + threadIdx.x;
  if (i >= n4) return;
  float4 v = ((const float4*)in)[i];
  bf16 o[4] = {__float2bfloat16(v.x), __float2bfloat16(v.y),
               __float2bfloat16(v.z), __float2bfloat16(v.w)};
  ((ulong1*)out)[i] = *(ulong1*)o;
}

// ---------------------------------------------------------------------------
// LayerNorm (optionally fused with residual add): one block per row of D_=1024
// ---------------------------------------------------------------------------
template <bool FUSE, typename TA, typename TS>
__global__ __launch_bounds__(256) void resid_ln_kernel(
    const TA* __restrict__ a, const TS* __restrict__ skip,
    const float* __restrict__ w, const float* __restrict__ bias,
    bf16* __restrict__ x2, bf16* __restrict__ hout, float st, float s1t) {
  const int row = blockIdx.x;
  const int tid = threadIdx.x;
  const int base = tid * 4;
  const size_t roff = (size_t)row * D_;

  float xv[4];
#pragma unroll
  for (int i = 0; i < 4; i++) {
    float v = tof(a[roff + base + i]);
    if (FUSE) v = st * v + s1t * tof(skip[roff + base + i]);
    xv[i] = v;
  }
  if (FUSE) {
#pragma unroll
    for (int i = 0; i < 4; i++) x2[roff + base + i] = __float2bfloat16(xv[i]);
  }

  float ls = 0.f, lq = 0.f;
#pragma unroll
  for (int i = 0; i < 4; i++) { ls += xv[i]; lq += xv[i] * xv[i]; }

  __shared__ float ssum[256];
  __shared__ float ssq[256];
  ssum[tid] = ls; ssq[tid] = lq;
  __syncthreads();
  for (int off = 128; off > 0; off >>= 1) {
    if (tid < off) { ssum[tid] += ssum[tid + off]; ssq[tid] += ssq[tid + off]; }
    __syncthreads();
  }
  const float mean = ssum[0] * (1.0f / D_);
  const float var  = ssq[0] * (1.0f / D_) - mean * mean;
  const float rstd = rsqrtf(var + 1e-5f);

#pragma unroll
  for (int i = 0; i < 4; i++) {
    float v = (xv[i] - mean) * rstd * w[base + i] + bias[base + i];
    hout[roff + base + i] = __float2bfloat16(v);
  }
}

// ---------------------------------------------------------------------------
// MFMA GEMM: C[M,N] = epilogue( A[M,K] @ Bw[N,K]^T ), both bf16.
// 128x128 tile, BK=32, 4 waves 2x2, each wave 4x4 frags of 16x16x32.
// ---------------------------------------------------------------------------
template <int EPI, typename TC>
__global__ __launch_bounds__(256) void gemm_mfma(
    const bf16* __restrict__ A, const bf16* __restrict__ Bw,
    TC* __restrict__ C, int M, int N, int K, float scale,
    const float* __restrict__ bias, const bf16* __restrict__ resid,
    float st, float s1t) {
  __shared__ __align__(16) bf16 As[128][32];
  __shared__ __align__(16) bf16 Bs[128][32];

  const int tid = threadIdx.x;
  const int lane = tid & 63;
  const int w = tid >> 6;
  const int wm = (w >> 1) * 64;
  const int wn = (w & 1) * 64;
  const int quad = lane >> 4;
  const int l16 = lane & 15;
  const int bm = blockIdx.y * 128, bn = blockIdx.x * 128;

  floatx4 acc[4][4];
#pragma unroll
  for (int i = 0; i < 4; i++)
#pragma unroll
    for (int j = 0; j < 4; j++) acc[i][j] = {0.f, 0.f, 0.f, 0.f};

  const int r0 = tid >> 2, o0 = (tid & 3) * 8;
  const int r1 = (tid + 256) >> 2, o1 = ((tid + 256) & 3) * 8;
  const bf16* Ap0 = A + (size_t)(bm + r0) * K + o0;
  const bf16* Ap1 = A + (size_t)(bm + r1) * K + o1;
  const bf16* Bp0 = Bw + (size_t)(bn + r0) * K + o0;
  const bf16* Bp1 = Bw + (size_t)(bn + r1) * K + o1;

  for (int k0 = 0; k0 < K; k0 += 32) {
    __syncthreads();
    ((uint4*)As)[tid]       = *(const uint4*)(Ap0 + k0);
    ((uint4*)As)[tid + 256] = *(const uint4*)(Ap1 + k0);
    ((uint4*)Bs)[tid]       = *(const uint4*)(Bp0 + k0);
    ((uint4*)Bs)[tid + 256] = *(const uint4*)(Bp1 + k0);
    __syncthreads();

    short8 af[4], bf[4];
#pragma unroll
    for (int f = 0; f < 4; f++) {
      af[f] = *(const short8*)&As[wm + f * 16 + l16][quad * 8];
      bf[f] = *(const short8*)&Bs[wn + f * 16 + l16][quad * 8];
    }
#pragma unroll
    for (int fi = 0; fi < 4; fi++)
#pragma unroll
      for (int fj = 0; fj < 4; fj++)
        acc[fi][fj] = __builtin_amdgcn_mfma_f32_16x16x32_bf16(
            af[fi], bf[fj], acc[fi][fj], 0, 0, 0);
  }

#pragma unroll
  for (int fi = 0; fi < 4; fi++) {
#pragma unroll
    for (int fj = 0; fj < 4; fj++) {
      const int col = bn + wn + fj * 16 + l16;
#pragma unroll
      for (int r = 0; r < 4; r++) {
        const int row = bm + wm + fi * 16 + quad * 4 + r;
        float v = acc[fi][fj][r];
        if (EPI == 0) {
          v *= scale;
        } else if (EPI == 1) {
          v = (v + bias[col]) * scale;
          v = 0.5f * v * (1.0f + erff(v * 0.70710678118654752f)) * st;
        } else {
          v = (v + bias[col]) * scale;
          v = st * v + s1t * __bfloat162float(resid[(size_t)row * N + col]);
        }
        stf(C, (size_t)row * N + col, v);
      }
    }
  }
}

// ---------------------------------------------------------------------------
// De-interleave qkv: qkv[b,s, d*48 + z*16 + h] -> QKV[z][b][h][s][d]
// ---------------------------------------------------------------------------
__global__ __launch_bounds__(256) void extract_qkv(
    const bf16* __restrict__ qkv, bf16* __restrict__ QKV) {
  size_t i = (size_t)blockIdx.x * 256 + threadIdx.x;
  const int d = (int)(i & 63);
  size_t r = i >> 6;
  const int ss = (int)(r & (S_ - 1)); r >>= 11;
  const int hh = (int)(r & (H_ - 1)); r >>= 4;
  const int bb = (int)(r & 1);
  const int z  = (int)(r >> 1);
  const int row = bb * S_ + ss;
  const int col = d * 48 + z * 16 + hh;
  QKV[i] = qkv[(size_t)row * D3_ + col];
}

// ---------------------------------------------------------------------------
// MFMA flash attention. Block = (64 Q-rows, head h, batch b), 256 thr / 4 waves.
// Wave wv owns Q-rows [wv*16, wv*16+16). Fragment scheme identical to
// gemm_mfma (A @ Bw^T): QK^T uses Bw=K (natural), PV uses Bw=V^T (Vt tile).
// Online softmax in registers; row group = 16 lanes (l16), stats reduced via
// shfl_xor 1/2/4/8. C-layout: col=l16, row=quad*4+r.
// ---------------------------------------------------------------------------
__global__ __launch_bounds__(256) void flash_attn_mfma(
    const bf16* __restrict__ Q, const bf16* __restrict__ K,
    const bf16* __restrict__ V, bf16* __restrict__ att,
    float mm_scale, float out_scale) {
  const int qb = blockIdx.x * 64;
  const int h = blockIdx.y, b = blockIdx.z;
  const int bh = b * H_ + h;
  const int tid = threadIdx.x;
  const int lane = tid & 63;
  const int wv = tid >> 6;
  const int quad = lane >> 4;
  const int l16 = lane & 15;

  // stride 72 (=16B-aligned rows, +8 pad) breaks the 128B-stride bank pattern
  __shared__ __align__(16) bf16 Ks[64][72];
  __shared__ __align__(16) bf16 Vt[64][72];   // Vt[d][j] = V[j][d]
  __shared__ __align__(16) bf16 Ps[64][72];   // P natural [m][j], wave-private rows

  const bf16* Qb_ = Q + (size_t)bh * S_ * DH_;
  const bf16* Kb_ = K + (size_t)bh * S_ * DH_;
  const bf16* Vb_ = V + (size_t)bh * S_ * DH_;

  // Q fragments (held in registers all kernel): row m = qb + wv*16 + l16
  short8 aq0, aq1;
  {
    const bf16* qrow = Qb_ + (size_t)(qb + wv * 16 + l16) * DH_ + quad * 8;
    aq0 = *(const short8*)(qrow);
    aq1 = *(const short8*)(qrow + 32);
  }

  float m_r[4], l_r[4];
#pragma unroll
  for (int r = 0; r < 4; r++) { m_r[r] = -1e30f; l_r[r] = 0.f; }
  floatx4 o[4];
#pragma unroll
  for (int fd = 0; fd < 4; fd++) o[fd] = {0.f, 0.f, 0.f, 0.f};

  // staging assignments
  const int kr0 = tid >> 3, ko0 = (tid & 7) * 8;           // K chunk 0
  const int kr1 = (tid + 256) >> 3, ko1 = (tid & 7) * 8;   // K chunk 1 (same ko)
  const int vj0 = tid & 63, vd0 = (tid >> 6) * 8;          // V chunk 0
  const int vj1 = tid & 63, vd1 = ((tid + 256) >> 6) * 8;  // V chunk 1

  for (int t = 0; t < S_ / 64; t++) {
    __syncthreads();
    // stage K natural [j][d]
    *(uint4*)&Ks[kr0][ko0] = *(const uint4*)(Kb_ + (size_t)(t * 64 + kr0) * DH_ + ko0);
    *(uint4*)&Ks[kr1][ko1] = *(const uint4*)(Kb_ + (size_t)(t * 64 + kr1) * DH_ + ko1);
    // stage V transposed: read row j (8 d's), scatter to Vt[d][j]
    {
      bf16 tmp[8];
      *(uint4*)tmp = *(const uint4*)(Vb_ + (size_t)(t * 64 + vj0) * DH_ + vd0);
#pragma unroll
      for (int e = 0; e < 8; e++) Vt[vd0 + e][vj0] = tmp[e];
      *(uint4*)tmp = *(const uint4*)(Vb_ + (size_t)(t * 64 + vj1) * DH_ + vd1);
#pragma unroll
      for (int e = 0; e < 8; e++) Vt[vd1 + e][vj1] = tmp[e];
    }
    __syncthreads();

    // S = Q K^T for wave's 16 rows x 64 keys
    float s[4][4];
#pragma unroll
    for (int fj = 0; fj < 4; fj++) {
      short8 bk0 = *(const short8*)&Ks[fj * 16 + l16][quad * 8];
      short8 bk1 = *(const short8*)&Ks[fj * 16 + l16][32 + quad * 8];
      floatx4 acc = {0.f, 0.f, 0.f, 0.f};
      acc = __builtin_amdgcn_mfma_f32_16x16x32_bf16(aq0, bk0, acc, 0, 0, 0);
      acc = __builtin_amdgcn_mfma_f32_16x16x32_bf16(aq1, bk1, acc, 0, 0, 0);
#pragma unroll
      for (int r = 0; r < 4; r++) s[fj][r] = acc[r] * mm_scale;
    }

    // online softmax, per C-layout row r (global row wv*16 + quad*4 + r)
#pragma unroll
    for (int r = 0; r < 4; r++) {
      float mx = fmaxf(fmaxf(s[0][r], s[1][r]), fmaxf(s[2][r], s[3][r]));
      mx = fmaxf(mx, __shfl_xor(mx, 1));
      mx = fmaxf(mx, __shfl_xor(mx, 2));
      mx = fmaxf(mx, __shfl_xor(mx, 4));
      mx = fmaxf(mx, __shfl_xor(mx, 8));
      const float mo = m_r[r];
      const float mn = fmaxf(mo, mx);
      m_r[r] = mn;
      const float alpha = __expf(mo - mn);
      float rs = 0.f;
#pragma unroll
      for (int fj = 0; fj < 4; fj++) {
        const float p = __expf(s[fj][r] - mn);
        rs += p;
        Ps[wv * 16 + quad * 4 + r][fj * 16 + l16] = __float2bfloat16(p);
      }
      rs += __shfl_xor(rs, 1);
      rs += __shfl_xor(rs, 2);
      rs += __shfl_xor(rs, 4);
      rs += __shfl_xor(rs, 8);
      l_r[r] = alpha * l_r[r] + rs;
#pragma unroll
      for (int fd = 0; fd < 4; fd++) o[fd][r] *= alpha;
    }

    // O += P V   (Ps rows are wave-private; lgkmcnt ordering handles RAW)
    short8 ap0 = *(const short8*)&Ps[wv * 16 + l16][quad * 8];
    short8 ap1 = *(const short8*)&Ps[wv * 16 + l16][32 + quad * 8];
#pragma unroll
    for (int fd = 0; fd < 4; fd++) {
      short8 bv0 = *(const short8*)&Vt[fd * 16 + l16][quad * 8];
      short8 bv1 = *(const short8*)&Vt[fd * 16 + l16][32 + quad * 8];
      o[fd] = __builtin_amdgcn_mfma_f32_16x16x32_bf16(ap0, bv0, o[fd], 0, 0, 0);
      o[fd] = __builtin_amdgcn_mfma_f32_16x16x32_bf16(ap1, bv1, o[fd], 0, 0, 0);
    }
  }

  // epilogue: out = o * out_scale / l
#pragma unroll
  for (int r = 0; r < 4; r++) {
    const float sc = out_scale / l_r[r];
    const size_t base =
        ((size_t)(b * S_ + qb + wv * 16 + quad * 4 + r)) * D_ + h * DH_;
#pragma unroll
    for (int fd = 0; fd < 4; fd++)
      att[base + fd * 16 + l16] = __float2bfloat16(o[fd][r] * sc);
  }
}

// ---------------------------------------------------------------------------
extern "C" void kernel_launch(void* const* d_in, const int* in_sizes, int n_in,
                              void* d_out, int out_size, void* d_ws, size_t ws_size,
                              hipStream_t stream) {
  const float* x     = (const float*)d_in[0];
  const float* w_qkv = (const float*)d_in[1];
  const float* w_o   = (const float*)d_in[2];
  const float* w1    = (const float*)d_in[3];
  const float* b1    = (const float*)d_in[4];
  const float* w2    = (const float*)d_in[5];
  const float* b2    = (const float*)d_in[6];
  const float* ln1w  = (const float*)d_in[7];
  const float* ln1b  = (const float*)d_in[8];
  const float* ln2w  = (const float*)d_in[9];
  const float* ln2b  = (const float*)d_in[10];
  float* out = (float*)d_out;
  bf16* ws  = (bf16*)d_ws;

  // workspace layout (bf16 elements), with reuse (peak 29,360,128 els = 58.7 MB)
  bf16* h1       = ws;                 // LN1 out; dead after QKV gemm
  bf16* Qb       = ws + 4194304;
  bf16* Kb       = ws + 8388608;
  bf16* Vb       = ws + 12582912;      // Q/K/V dead after flash
  bf16* qkv      = ws + 16777216;      // dead after extract
  bf16* att      = ws;                 // = h1 region
  bf16* attn_out = ws + 16777216;      // dead after LN2
  bf16* x2       = ws + 20971520;
  bf16* h2       = ws + 25165824;
  bf16* g        = ws;                 // h1+Q/K/V regions (dead)
  bf16* wqb      = ws + 4194304;       // overwritten by extract (ok)
  bf16* wob      = ws + 4194304;       // Q region, dead after flash
  bf16* w1b      = ws + 16777216;      // attn_out region, dead
  bf16* w2b      = ws + 16777216;      // w1b dead after FFN1

  const float MM_SCALE   = (float)pow((double)S_ * S_ * DH_, -1.0 / 6.0);
  const float SM_SCALE   = (float)((double)S_ / sqrt(1.31 * 1.65));
  const float GELU_SCALE = (float)pow(0.588 * 0.675, -0.5);
  const float SQRT_TAU   = (float)sqrt(0.2);
  const float SQRT_1MT   = (float)sqrt(0.8);
  const float qkv_scale  = (float)pow((double)D_ * D3_, -0.25);
  const float o_scale    = (float)pow((double)D_ * D_, -0.25);
  const float w1_scale   = (float)pow((double)D_ * DF_, -0.25);
  const float w2_scale   = (float)pow((double)DF_ * D_, -0.25);

  // 1. LN1
  resid_ln_kernel<false, float, float><<<BS_, 256, 0, stream>>>(
      x, nullptr, ln1w, ln1b, nullptr, h1, 0.f, 0.f);
  // 2. convert w_qkv; QKV gemm
  cvt_f32_bf16<<<(D3_ * D_ / 4 + 255) / 256, 256, 0, stream>>>(w_qkv, wqb, D3_ * D_ / 4);
  gemm_mfma<0, bf16><<<dim3(D3_ / 128, BS_ / 128), 256, 0, stream>>>(
      h1, wqb, qkv, BS_, D3_, D_, qkv_scale, nullptr, nullptr, 0.f, 0.f);
  // 3. de-interleave
  extract_qkv<<<(3 * BS_ * D_) / 256, 256, 0, stream>>>(qkv, Qb);
  // 4. MFMA flash attention
  flash_attn_mfma<<<dim3(S_ / 64, H_, B_), 256, 0, stream>>>(
      Qb, Kb, Vb, att, MM_SCALE, SM_SCALE * MM_SCALE);
  // 5. convert w_o; out-proj
  cvt_f32_bf16<<<(D_ * D_ / 4 + 255) / 256, 256, 0, stream>>>(w_o, wob, D_ * D_ / 4);
  gemm_mfma<0, bf16><<<dim3(D_ / 128, BS_ / 128), 256, 0, stream>>>(
      att, wob, attn_out, BS_, D_, D_, o_scale, nullptr, nullptr, 0.f, 0.f);
  // 6. residual + LN2
  resid_ln_kernel<true, bf16, float><<<BS_, 256, 0, stream>>>(
      attn_out, x, ln2w, ln2b, x2, h2, SQRT_TAU, SQRT_1MT);
  // 7. convert w1; FFN1 + GELU
  cvt_f32_bf16<<<(DF_ * D_ / 4 + 255) / 256, 256, 0, stream>>>(w1, w1b, DF_ * D_ / 4);
  gemm_mfma<1, bf16><<<dim3(DF_ / 128, BS_ / 128), 256, 0, stream>>>(
      h2, w1b, g, BS_, DF_, D_, w1_scale, b1, nullptr, GELU_SCALE, 0.f);
  // 8. convert w2; FFN2 + bias + final residual -> d_out (fp32)
  cvt_f32_bf16<<<(D_ * DF_ / 4 + 255) / 256, 256, 0, stream>>>(w2, w2b, D_ * DF_ / 4);
  gemm_mfma<2, float><<<dim3(D_ / 128, BS_ / 128), 256, 0, stream>>>(
      g, w2b, out, BS_, D_, DF_, w2_scale, b2, x2, SQRT_TAU, SQRT_1MT);
}